// Round 1
// baseline (436.247 us; speedup 1.0000x reference)
//
#include <hip/hip_runtime.h>
#include <hip/hip_bf16.h>

#define LUT_S 33
#define LUT_P (LUT_S*LUT_S*LUT_S)   // 35937
#define IMG_H 1080
#define IMG_W 1920
#define TH 256
#define TW 256

// ---------------- Kernel A: W-resize (antialias triangle, kscale=7.5) -------
// img [B*3, 1080, 1920] -> tmp [B*3, 1080, 256]
__global__ void resize_w_kernel(const float* __restrict__ img,
                                float* __restrict__ tmp, int total) {
    int e = blockIdx.x * blockDim.x + threadIdx.x;
    if (e >= total) return;
    int ow = e & 255;
    int r  = e >> 8;            // row index over B*3*1080
    const float kscale = 7.5f;  // 1920/256
    float sf = (ow + 0.5f) * 7.5f - 0.5f;
    int lo = (int)ceilf(sf - kscale); if (lo < 0) lo = 0;
    int hi = (int)floorf(sf + kscale); if (hi > IMG_W - 1) hi = IMG_W - 1;
    const float* row = img + (size_t)r * IMG_W;
    float acc = 0.f, wsum = 0.f;
    for (int i = lo; i <= hi; ++i) {
        float w = 1.0f - fabsf(sf - (float)i) * (1.0f / 7.5f);
        if (w > 0.f) { acc += w * row[i]; wsum += w; }
    }
    tmp[e] = acc / wsum;
}

// ---------------- Kernel B: H-resize (kscale=4.21875) -----------------------
// tmp [B*3, 1080, 256] -> thumb [B*3, 256, 256]
__global__ void resize_h_kernel(const float* __restrict__ tmp,
                                float* __restrict__ thumb, int total) {
    int e = blockIdx.x * blockDim.x + threadIdx.x;
    if (e >= total) return;
    int ow = e & 255;
    int oh = (e >> 8) & 255;
    int pl = e >> 16;           // plane over B*3
    const float kscale = 4.21875f;  // 1080/256
    float sf = (oh + 0.5f) * 4.21875f - 0.5f;
    int lo = (int)ceilf(sf - kscale); if (lo < 0) lo = 0;
    int hi = (int)floorf(sf + kscale); if (hi > IMG_H - 1) hi = IMG_H - 1;
    const float* col = tmp + (size_t)pl * IMG_H * TW + ow;
    float acc = 0.f, wsum = 0.f;
    for (int i = lo; i <= hi; ++i) {
        float w = 1.0f - fabsf(sf - (float)i) * (1.0f / 4.21875f);
        if (w > 0.f) { acc += w * col[(size_t)i * TW]; wsum += w; }
    }
    thumb[e] = acc / wsum;
}

// ---------------- Kernel C1: conv1 3->16, stride2, SAME(pad_lo=0), relu ----
// thumb [B,3,256,256] -> c1 [B,16,128,128]
__global__ void conv1_kernel(const float* __restrict__ thumb,
                             const float* __restrict__ w,
                             const float* __restrict__ bias,
                             float* __restrict__ out, int total) {
    int e = blockIdx.x * blockDim.x + threadIdx.x;
    if (e >= total) return;
    int ow = e & 127;
    int oh = (e >> 7) & 127;
    int oc = (e >> 14) & 15;
    int b  = e >> 18;
    float acc = bias[oc];
    for (int ic = 0; ic < 3; ++ic) {
        const float* tp = thumb + ((size_t)(b * 3 + ic) * 256) * 256;
        const float* wp = w + ((oc * 3 + ic) * 9);
        #pragma unroll
        for (int kh = 0; kh < 3; ++kh) {
            int ih = oh * 2 + kh;
            if (ih >= 256) continue;
            #pragma unroll
            for (int kw = 0; kw < 3; ++kw) {
                int iw = ow * 2 + kw;
                if (iw >= 256) continue;
                acc += tp[ih * 256 + iw] * wp[kh * 3 + kw];
            }
        }
    }
    out[e] = fmaxf(acc, 0.f);
}

// ---------------- Kernel C2: conv2 16->32, stride2, SAME(pad_lo=0), relu ---
// c1 [B,16,128,128] -> c2 [B,32,64,64]
__global__ void conv2_kernel(const float* __restrict__ c1,
                             const float* __restrict__ w,
                             const float* __restrict__ bias,
                             float* __restrict__ out, int total) {
    int e = blockIdx.x * blockDim.x + threadIdx.x;
    if (e >= total) return;
    int ow = e & 63;
    int oh = (e >> 6) & 63;
    int oc = (e >> 12) & 31;
    int b  = e >> 17;
    float acc = bias[oc];
    for (int ic = 0; ic < 16; ++ic) {
        const float* ip = c1 + ((size_t)(b * 16 + ic) * 128) * 128;
        const float* wp = w + ((oc * 16 + ic) * 9);
        #pragma unroll
        for (int kh = 0; kh < 3; ++kh) {
            int ih = oh * 2 + kh;
            if (ih >= 128) continue;
            #pragma unroll
            for (int kw = 0; kw < 3; ++kw) {
                int iw = ow * 2 + kw;
                if (iw >= 128) continue;
                acc += ip[ih * 128 + iw] * wp[kh * 3 + kw];
            }
        }
    }
    out[e] = fmaxf(acc, 0.f);
}

// ---------------- Kernel D1: global average pool -> pooled [B*32] -----------
__global__ void pool_kernel(const float* __restrict__ c2,
                            float* __restrict__ pooled) {
    int bc = blockIdx.x;   // b*32 + ch
    const float* p = c2 + (size_t)bc * 4096;
    float s = 0.f;
    for (int i = threadIdx.x; i < 4096; i += 256) s += p[i];
    #pragma unroll
    for (int off = 32; off > 0; off >>= 1) s += __shfl_down(s, off, 64);
    __shared__ float part[4];
    if ((threadIdx.x & 63) == 0) part[threadIdx.x >> 6] = s;
    __syncthreads();
    if (threadIdx.x == 0)
        pooled[bc] = (part[0] + part[1] + part[2] + part[3]) * (1.0f / 4096.0f);
}

// ---------------- Kernel D2: dense + softmax -> weights [B*3] --------------
__global__ void head_kernel(const float* __restrict__ pooled,
                            const float* __restrict__ dw,
                            const float* __restrict__ db,
                            float* __restrict__ wts, int B) {
    __shared__ float sp[8 * 32];
    __shared__ float lg[8 * 3];
    int t = threadIdx.x;
    if (t < B * 32) sp[t] = pooled[t];
    __syncthreads();
    if (t < B * 3) {
        int b = t / 3, n = t - b * 3;
        float acc = db[n];
        for (int ch = 0; ch < 32; ++ch) acc += sp[b * 32 + ch] * dw[ch * 3 + n];
        lg[t] = acc;
    }
    __syncthreads();
    if (t < B) {
        float a = lg[t * 3 + 0], bb = lg[t * 3 + 1], c = lg[t * 3 + 2];
        float m = fmaxf(a, fmaxf(bb, c));
        float e0 = expf(a - m), e1 = expf(bb - m), e2 = expf(c - m);
        float inv = 1.0f / (e0 + e1 + e2);
        wts[t * 3 + 0] = e0 * inv;
        wts[t * 3 + 1] = e1 * inv;
        wts[t * 3 + 2] = e2 * inv;
    }
}

// ---------------- Kernel E: blend basis LUTs -> float4 LUT per batch --------
// basis [3, 35937, 3]; blut [B, 35937] float4 (rgb + pad)
__global__ void blend_kernel(const float* __restrict__ basis,
                             const float* __restrict__ wts,
                             float4* __restrict__ blut, int total) {
    int e = blockIdx.x * blockDim.x + threadIdx.x;
    if (e >= total) return;
    int b = e / LUT_P;
    int p = e - b * LUT_P;
    float w0 = wts[b * 3 + 0], w1 = wts[b * 3 + 1], w2 = wts[b * 3 + 2];
    const float* b0 = basis + (size_t)p * 3;
    const float* b1 = basis + (size_t)LUT_P * 3 + (size_t)p * 3;
    const float* b2 = basis + (size_t)2 * LUT_P * 3 + (size_t)p * 3;
    blut[e] = make_float4(w0 * b0[0] + w1 * b1[0] + w2 * b2[0],
                          w0 * b0[1] + w1 * b1[1] + w2 * b2[1],
                          w0 * b0[2] + w1 * b1[2] + w2 * b2[2], 0.f);
}

// ---------------- Kernel F: apply LUT (trilinear), 4 px / thread ------------
__device__ __forceinline__ float trilerp(float c000, float c001, float c010, float c011,
                                         float c100, float c101, float c110, float c111,
                                         float wx0, float wx1, float wy0, float wy1,
                                         float wz0, float wz1) {
    return wz0 * (wy0 * (wx0 * c000 + wx1 * c001) + wy1 * (wx0 * c010 + wx1 * c011))
         + wz1 * (wy0 * (wx0 * c100 + wx1 * c101) + wy1 * (wx0 * c110 + wx1 * c111));
}

__global__ void apply_lut_kernel(const float* __restrict__ img,
                                 const float4* __restrict__ blut,
                                 float* __restrict__ out, int total_quads) {
    const int P  = IMG_H * IMG_W;       // 2,073,600
    const int QP = P / 4;               // 518,400
    int t = blockIdx.x * blockDim.x + threadIdx.x;
    if (t >= total_quads) return;
    int b = t / QP;
    int q = t - b * QP;
    const float4* lut = blut + (size_t)b * LUT_P;
    size_t base = (size_t)b * 3 * P + (size_t)q * 4;
    float4 R = *(const float4*)(img + base);
    float4 G = *(const float4*)(img + base + P);
    float4 Bl = *(const float4*)(img + base + 2 * (size_t)P);
    float4 Ro, Go, Bo;
    float* rp = (float*)&R; float* gp = (float*)&G; float* bp = (float*)&Bl;
    float* rop = (float*)&Ro; float* gop = (float*)&Go; float* bop = (float*)&Bo;
    #pragma unroll
    for (int k = 0; k < 4; ++k) {
        float pr = fminf(fmaxf(rp[k], 0.f), 1.f) * (float)(LUT_S - 1);
        float pg = fminf(fmaxf(gp[k], 0.f), 1.f) * (float)(LUT_S - 1);
        float pb = fminf(fmaxf(bp[k], 0.f), 1.f) * (float)(LUT_S - 1);
        int ix = (int)pr; if (ix > LUT_S - 2) ix = LUT_S - 2;
        int iy = (int)pg; if (iy > LUT_S - 2) iy = LUT_S - 2;
        int iz = (int)pb; if (iz > LUT_S - 2) iz = LUT_S - 2;
        float fx = pr - (float)ix, fy = pg - (float)iy, fz = pb - (float)iz;
        // axis map: x<-R (fastest), y<-G, z<-B; idx=(z*33+y)*33+x
        int i000 = (iz * LUT_S + iy) * LUT_S + ix;
        float4 c000 = lut[i000];
        float4 c001 = lut[i000 + 1];
        float4 c010 = lut[i000 + LUT_S];
        float4 c011 = lut[i000 + LUT_S + 1];
        float4 c100 = lut[i000 + LUT_S * LUT_S];
        float4 c101 = lut[i000 + LUT_S * LUT_S + 1];
        float4 c110 = lut[i000 + LUT_S * LUT_S + LUT_S];
        float4 c111 = lut[i000 + LUT_S * LUT_S + LUT_S + 1];
        float wx0 = 1.f - fx, wx1 = fx;
        float wy0 = 1.f - fy, wy1 = fy;
        float wz0 = 1.f - fz, wz1 = fz;
        float orv = trilerp(c000.x, c001.x, c010.x, c011.x, c100.x, c101.x, c110.x, c111.x,
                            wx0, wx1, wy0, wy1, wz0, wz1);
        float ogv = trilerp(c000.y, c001.y, c010.y, c011.y, c100.y, c101.y, c110.y, c111.y,
                            wx0, wx1, wy0, wy1, wz0, wz1);
        float obv = trilerp(c000.z, c001.z, c010.z, c011.z, c100.z, c101.z, c110.z, c111.z,
                            wx0, wx1, wy0, wy1, wz0, wz1);
        rop[k] = fminf(fmaxf(orv, 0.f), 1.f);
        gop[k] = fminf(fmaxf(ogv, 0.f), 1.f);
        bop[k] = fminf(fmaxf(obv, 0.f), 1.f);
    }
    *(float4*)(out + base)               = Ro;
    *(float4*)(out + base + P)           = Go;
    *(float4*)(out + base + 2 * (size_t)P) = Bo;
}

extern "C" void kernel_launch(void* const* d_in, const int* in_sizes, int n_in,
                              void* d_out, int out_size, void* d_ws, size_t ws_size,
                              hipStream_t stream) {
    const float* img     = (const float*)d_in[0];
    const float* basis   = (const float*)d_in[1];
    const float* conv1_w = (const float*)d_in[2];
    const float* conv1_b = (const float*)d_in[3];
    const float* conv2_w = (const float*)d_in[4];
    const float* conv2_b = (const float*)d_in[5];
    const float* dense_w = (const float*)d_in[6];
    const float* dense_b = (const float*)d_in[7];
    float* out = (float*)d_out;

    const size_t P = (size_t)IMG_H * IMG_W;
    int B = (int)(in_sizes[0] / (3 * P));   // 4

    // workspace layout (floats)
    float* ws = (float*)d_ws;
    size_t off = 0;
    float* tmp1   = ws + off; off += (size_t)B * 3 * IMG_H * TW;   // W-resized
    float* thumb  = ws + off; off += (size_t)B * 3 * TH * TW;
    float* c1     = ws + off; off += (size_t)B * 16 * 128 * 128;
    float* c2     = ws + off; off += (size_t)B * 32 * 64 * 64;
    float* pooled = ws + off; off += (size_t)B * 32;
    float* wts    = ws + off; off += (size_t)B * 3;
    off = (off + 3) & ~(size_t)3;                                  // 16B align
    float4* blut  = (float4*)(ws + off); off += (size_t)B * LUT_P * 4;

    const int TPB = 256;
    {   // A: W-resize
        int total = B * 3 * IMG_H * TW;
        resize_w_kernel<<<(total + TPB - 1) / TPB, TPB, 0, stream>>>(img, tmp1, total);
    }
    {   // B: H-resize
        int total = B * 3 * TH * TW;
        resize_h_kernel<<<(total + TPB - 1) / TPB, TPB, 0, stream>>>(tmp1, thumb, total);
    }
    {   // C1
        int total = B * 16 * 128 * 128;
        conv1_kernel<<<(total + TPB - 1) / TPB, TPB, 0, stream>>>(thumb, conv1_w, conv1_b, c1, total);
    }
    {   // C2
        int total = B * 32 * 64 * 64;
        conv2_kernel<<<(total + TPB - 1) / TPB, TPB, 0, stream>>>(c1, conv2_w, conv2_b, c2, total);
    }
    {   // D1: pool
        pool_kernel<<<B * 32, TPB, 0, stream>>>(c2, pooled);
    }
    {   // D2: dense + softmax
        head_kernel<<<1, TPB, 0, stream>>>(pooled, dense_w, dense_b, wts, B);
    }
    {   // E: blend
        int total = B * LUT_P;
        blend_kernel<<<(total + TPB - 1) / TPB, TPB, 0, stream>>>(basis, wts, blut, total);
    }
    {   // F: apply
        int total = B * (int)(P / 4);
        apply_lut_kernel<<<(total + TPB - 1) / TPB, TPB, 0, stream>>>(img, blut, out, total);
    }
}

// Round 2
// 436.136 us; speedup vs baseline: 1.0003x; 1.0003x over previous
//
#include <hip/hip_runtime.h>
#include <hip/hip_bf16.h>
#include <hip/hip_fp16.h>

#define LUT_S 33
#define LUT_P (LUT_S*LUT_S*LUT_S)   // 35937
#define IMG_H 1080
#define IMG_W 1920
#define TH 256
#define TW 256

// ---------------- Kernel A: W-resize (antialias triangle, kscale=7.5) -------
// img [B*3, 1080, 1920] -> tmp [B*3, 1080, 256]
__global__ void resize_w_kernel(const float* __restrict__ img,
                                float* __restrict__ tmp, int total) {
    int e = blockIdx.x * blockDim.x + threadIdx.x;
    if (e >= total) return;
    int ow = e & 255;
    int r  = e >> 8;            // row index over B*3*1080
    const float kscale = 7.5f;  // 1920/256
    float sf = (ow + 0.5f) * 7.5f - 0.5f;
    int lo = (int)ceilf(sf - kscale); if (lo < 0) lo = 0;
    int hi = (int)floorf(sf + kscale); if (hi > IMG_W - 1) hi = IMG_W - 1;
    const float* row = img + (size_t)r * IMG_W;
    float acc = 0.f, wsum = 0.f;
    for (int i = lo; i <= hi; ++i) {
        float w = 1.0f - fabsf(sf - (float)i) * (1.0f / 7.5f);
        if (w > 0.f) { acc += w * row[i]; wsum += w; }
    }
    tmp[e] = acc / wsum;
}

// ---------------- Kernel B: H-resize (kscale=4.21875) -----------------------
// tmp [B*3, 1080, 256] -> thumb [B*3, 256, 256]
__global__ void resize_h_kernel(const float* __restrict__ tmp,
                                float* __restrict__ thumb, int total) {
    int e = blockIdx.x * blockDim.x + threadIdx.x;
    if (e >= total) return;
    int ow = e & 255;
    int oh = (e >> 8) & 255;
    int pl = e >> 16;           // plane over B*3
    const float kscale = 4.21875f;  // 1080/256
    float sf = (oh + 0.5f) * 4.21875f - 0.5f;
    int lo = (int)ceilf(sf - kscale); if (lo < 0) lo = 0;
    int hi = (int)floorf(sf + kscale); if (hi > IMG_H - 1) hi = IMG_H - 1;
    const float* col = tmp + (size_t)pl * IMG_H * TW + ow;
    float acc = 0.f, wsum = 0.f;
    for (int i = lo; i <= hi; ++i) {
        float w = 1.0f - fabsf(sf - (float)i) * (1.0f / 4.21875f);
        if (w > 0.f) { acc += w * col[(size_t)i * TW]; wsum += w; }
    }
    thumb[e] = acc / wsum;
}

// ---------------- Kernel C1: conv1 3->16, stride2, SAME(pad_lo=0), relu ----
// thumb [B,3,256,256] -> c1 [B,16,128,128]
__global__ void conv1_kernel(const float* __restrict__ thumb,
                             const float* __restrict__ w,
                             const float* __restrict__ bias,
                             float* __restrict__ out, int total) {
    int e = blockIdx.x * blockDim.x + threadIdx.x;
    if (e >= total) return;
    int ow = e & 127;
    int oh = (e >> 7) & 127;
    int oc = (e >> 14) & 15;
    int b  = e >> 18;
    float acc = bias[oc];
    for (int ic = 0; ic < 3; ++ic) {
        const float* tp = thumb + ((size_t)(b * 3 + ic) * 256) * 256;
        const float* wp = w + ((oc * 3 + ic) * 9);
        #pragma unroll
        for (int kh = 0; kh < 3; ++kh) {
            int ih = oh * 2 + kh;
            if (ih >= 256) continue;
            #pragma unroll
            for (int kw = 0; kw < 3; ++kw) {
                int iw = ow * 2 + kw;
                if (iw >= 256) continue;
                acc += tp[ih * 256 + iw] * wp[kh * 3 + kw];
            }
        }
    }
    out[e] = fmaxf(acc, 0.f);
}

// ---------- Kernel C2+D1 fused: conv2 16->32 s2 relu + global avg pool ------
// c1 [B,16,128,128] -> pooled [B*32] (pre-zeroed; atomicAdd of wave partials)
__global__ void conv2_pool_kernel(const float* __restrict__ c1,
                                  const float* __restrict__ w,
                                  const float* __restrict__ bias,
                                  float* __restrict__ pooled, int total) {
    int e = blockIdx.x * blockDim.x + threadIdx.x;
    float val = 0.f;
    int oc = 0, b = 0;
    if (e < total) {
        int ow = e & 63;
        int oh = (e >> 6) & 63;
        oc = (e >> 12) & 31;
        b  = e >> 17;
        float acc = bias[oc];
        for (int ic = 0; ic < 16; ++ic) {
            const float* ip = c1 + ((size_t)(b * 16 + ic) * 128) * 128;
            const float* wp = w + ((oc * 16 + ic) * 9);
            #pragma unroll
            for (int kh = 0; kh < 3; ++kh) {
                int ih = oh * 2 + kh;
                if (ih >= 128) continue;
                #pragma unroll
                for (int kw = 0; kw < 3; ++kw) {
                    int iw = ow * 2 + kw;
                    if (iw >= 128) continue;
                    acc += ip[ih * 128 + iw] * wp[kh * 3 + kw];
                }
            }
        }
        val = fmaxf(acc, 0.f);
    }
    // all 64 lanes of a wave share (b, oc): e>>12 identical across a wave
    #pragma unroll
    for (int off = 32; off > 0; off >>= 1) val += __shfl_down(val, off, 64);
    if ((threadIdx.x & 63) == 0 && e < total)
        atomicAdd(&pooled[b * 32 + oc], val);
}

// ---------------- Kernel D2: dense + softmax -> weights [B*3] --------------
__global__ void head_kernel(const float* __restrict__ pooled,
                            const float* __restrict__ dw,
                            const float* __restrict__ db,
                            float* __restrict__ wts, int B) {
    __shared__ float sp[8 * 32];
    __shared__ float lg[8 * 3];
    int t = threadIdx.x;
    if (t < B * 32) sp[t] = pooled[t] * (1.0f / 4096.0f);
    __syncthreads();
    if (t < B * 3) {
        int b = t / 3, n = t - b * 3;
        float acc = db[n];
        for (int ch = 0; ch < 32; ++ch) acc += sp[b * 32 + ch] * dw[ch * 3 + n];
        lg[t] = acc;
    }
    __syncthreads();
    if (t < B) {
        float a = lg[t * 3 + 0], bb = lg[t * 3 + 1], c = lg[t * 3 + 2];
        float m = fmaxf(a, fmaxf(bb, c));
        float e0 = expf(a - m), e1 = expf(bb - m), e2 = expf(c - m);
        float inv = 1.0f / (e0 + e1 + e2);
        wts[t * 3 + 0] = e0 * inv;
        wts[t * 3 + 1] = e1 * inv;
        wts[t * 3 + 2] = e2 * inv;
    }
}

// ------- Kernel E: blend basis LUTs -> fp16 x-pair LUT per batch ------------
// basis [3, 35937, 3]; plut [B, 35937] entries of 16B:
//   {half2(r[p],r[p+1]), half2(g[p],g[p+1]), half2(b[p],b[p+1]), pad}
__global__ void blend_kernel(const float* __restrict__ basis,
                             const float* __restrict__ wts,
                             float4* __restrict__ plut, int total) {
    int e = blockIdx.x * blockDim.x + threadIdx.x;
    if (e >= total) return;
    int b = e / LUT_P;
    int p = e - b * LUT_P;
    int p1 = p + 1; if (p1 > LUT_P - 1) p1 = LUT_P - 1;
    float w0 = wts[b * 3 + 0], w1 = wts[b * 3 + 1], w2 = wts[b * 3 + 2];
    const float* b0 = basis;
    const float* b1 = basis + (size_t)LUT_P * 3;
    const float* b2 = basis + (size_t)2 * LUT_P * 3;
    size_t o0 = (size_t)p * 3, o1 = (size_t)p1 * 3;
    float r0 = w0 * b0[o0 + 0] + w1 * b1[o0 + 0] + w2 * b2[o0 + 0];
    float g0 = w0 * b0[o0 + 1] + w1 * b1[o0 + 1] + w2 * b2[o0 + 1];
    float bl0 = w0 * b0[o0 + 2] + w1 * b1[o0 + 2] + w2 * b2[o0 + 2];
    float r1 = w0 * b0[o1 + 0] + w1 * b1[o1 + 0] + w2 * b2[o1 + 0];
    float g1 = w0 * b0[o1 + 1] + w1 * b1[o1 + 1] + w2 * b2[o1 + 1];
    float bl1 = w0 * b0[o1 + 2] + w1 * b1[o1 + 2] + w2 * b2[o1 + 2];
    union { float4 f4; __half2 h2[4]; } u;
    u.h2[0] = __floats2half2_rn(r0, r1);
    u.h2[1] = __floats2half2_rn(g0, g1);
    u.h2[2] = __floats2half2_rn(bl0, bl1);
    u.h2[3] = __floats2half2_rn(0.f, 0.f);
    plut[e] = u.f4;
}

// ---------------- Kernel F: apply LUT (trilinear), 4 px / thread ------------
// 4 gathers/pixel: each 16B entry carries both x-neighbors (fp16).
__global__ __launch_bounds__(256)
void apply_lut_kernel(const float* __restrict__ img,
                      const float4* __restrict__ plut,
                      float* __restrict__ out, int total_quads) {
    const int P  = IMG_H * IMG_W;       // 2,073,600
    const int QP = P / 4;               // 518,400
    int t = blockIdx.x * blockDim.x + threadIdx.x;
    if (t >= total_quads) return;
    int b = t / QP;
    int q = t - b * QP;
    const float4* lut = plut + (size_t)b * LUT_P;
    size_t base = (size_t)b * 3 * P + (size_t)q * 4;
    float4 R = *(const float4*)(img + base);
    float4 G = *(const float4*)(img + base + P);
    float4 Bl = *(const float4*)(img + base + 2 * (size_t)P);
    float4 Ro, Go, Bo;
    float* rp = (float*)&R; float* gp = (float*)&G; float* bp = (float*)&Bl;
    float* rop = (float*)&Ro; float* gop = (float*)&Go; float* bop = (float*)&Bo;
    #pragma unroll
    for (int k = 0; k < 4; ++k) {
        float pr = fminf(fmaxf(rp[k], 0.f), 1.f) * (float)(LUT_S - 1);
        float pg = fminf(fmaxf(gp[k], 0.f), 1.f) * (float)(LUT_S - 1);
        float pb = fminf(fmaxf(bp[k], 0.f), 1.f) * (float)(LUT_S - 1);
        int ix = (int)pr; if (ix > LUT_S - 2) ix = LUT_S - 2;
        int iy = (int)pg; if (iy > LUT_S - 2) iy = LUT_S - 2;
        int iz = (int)pb; if (iz > LUT_S - 2) iz = LUT_S - 2;
        float fx = pr - (float)ix, fy = pg - (float)iy, fz = pb - (float)iz;
        // axis map: x<-R (fastest), y<-G, z<-B; idx=(z*33+y)*33+x
        int i000 = (iz * LUT_S + iy) * LUT_S + ix;
        float4 e00 = lut[i000];                       // (y0,z0) x-pair
        float4 e10 = lut[i000 + LUT_S];               // (y1,z0)
        float4 e01 = lut[i000 + LUT_S * LUT_S];       // (y0,z1)
        float4 e11 = lut[i000 + LUT_S * LUT_S + LUT_S];
        const __half2* h00 = (const __half2*)&e00;
        const __half2* h10 = (const __half2*)&e10;
        const __half2* h01 = (const __half2*)&e01;
        const __half2* h11 = (const __half2*)&e11;
        float wx0 = 1.f - fx, wx1 = fx;
        float wy0 = 1.f - fy, wy1 = fy;
        float wz0 = 1.f - fz, wz1 = fz;
        #pragma unroll
        for (int c = 0; c < 3; ++c) {
            float2 v00 = __half22float2(h00[c]);
            float2 v10 = __half22float2(h10[c]);
            float2 v01 = __half22float2(h01[c]);
            float2 v11 = __half22float2(h11[c]);
            float x00 = v00.x * wx0 + v00.y * wx1;    // (y0,z0)
            float x10 = v10.x * wx0 + v10.y * wx1;    // (y1,z0)
            float x01 = v01.x * wx0 + v01.y * wx1;    // (y0,z1)
            float x11 = v11.x * wx0 + v11.y * wx1;    // (y1,z1)
            float z0 = x00 * wy0 + x10 * wy1;
            float z1 = x01 * wy0 + x11 * wy1;
            float o = z0 * wz0 + z1 * wz1;
            o = fminf(fmaxf(o, 0.f), 1.f);
            if (c == 0) rop[k] = o; else if (c == 1) gop[k] = o; else bop[k] = o;
        }
    }
    *(float4*)(out + base)                 = Ro;
    *(float4*)(out + base + P)             = Go;
    *(float4*)(out + base + 2 * (size_t)P) = Bo;
}

extern "C" void kernel_launch(void* const* d_in, const int* in_sizes, int n_in,
                              void* d_out, int out_size, void* d_ws, size_t ws_size,
                              hipStream_t stream) {
    const float* img     = (const float*)d_in[0];
    const float* basis   = (const float*)d_in[1];
    const float* conv1_w = (const float*)d_in[2];
    const float* conv1_b = (const float*)d_in[3];
    const float* conv2_w = (const float*)d_in[4];
    const float* conv2_b = (const float*)d_in[5];
    const float* dense_w = (const float*)d_in[6];
    const float* dense_b = (const float*)d_in[7];
    float* out = (float*)d_out;

    const size_t P = (size_t)IMG_H * IMG_W;
    int B = (int)(in_sizes[0] / (3 * P));   // 4

    // workspace layout (floats)
    float* ws = (float*)d_ws;
    size_t off = 0;
    float* tmp1   = ws + off; off += (size_t)B * 3 * IMG_H * TW;   // W-resized
    float* thumb  = ws + off; off += (size_t)B * 3 * TH * TW;
    float* c1     = ws + off; off += (size_t)B * 16 * 128 * 128;
    float* pooled = ws + off; off += (size_t)B * 32;
    float* wts    = ws + off; off += (size_t)B * 3;
    off = (off + 3) & ~(size_t)3;                                  // 16B align
    float4* plut  = (float4*)(ws + off); off += (size_t)B * LUT_P * 4;

    const int TPB = 256;
    {   // A: W-resize
        int total = B * 3 * IMG_H * TW;
        resize_w_kernel<<<(total + TPB - 1) / TPB, TPB, 0, stream>>>(img, tmp1, total);
    }
    {   // B: H-resize
        int total = B * 3 * TH * TW;
        resize_h_kernel<<<(total + TPB - 1) / TPB, TPB, 0, stream>>>(tmp1, thumb, total);
    }
    {   // C1
        int total = B * 16 * 128 * 128;
        conv1_kernel<<<(total + TPB - 1) / TPB, TPB, 0, stream>>>(thumb, conv1_w, conv1_b, c1, total);
    }
    {   // C2 + pool (pooled must start zeroed; ws is poisoned 0xAA each call)
        hipMemsetAsync(pooled, 0, (size_t)B * 32 * sizeof(float), stream);
        int total = B * 32 * 64 * 64;
        conv2_pool_kernel<<<(total + TPB - 1) / TPB, TPB, 0, stream>>>(c1, conv2_w, conv2_b, pooled, total);
    }
    {   // D2: dense + softmax
        head_kernel<<<1, TPB, 0, stream>>>(pooled, dense_w, dense_b, wts, B);
    }
    {   // E: blend -> fp16 x-pair LUT
        int total = B * LUT_P;
        blend_kernel<<<(total + TPB - 1) / TPB, TPB, 0, stream>>>(basis, wts, plut, total);
    }
    {   // F: apply
        int total = B * (int)(P / 4);
        apply_lut_kernel<<<(total + TPB - 1) / TPB, TPB, 0, stream>>>(img, plut, out, total);
    }
}

// Round 3
// 362.854 us; speedup vs baseline: 1.2023x; 1.2020x over previous
//
#include <hip/hip_runtime.h>
#include <hip/hip_bf16.h>
#include <hip/hip_fp16.h>

#define LUT_S 33
#define LUT_P (LUT_S*LUT_S*LUT_S)   // 35937
#define CELLS 32768                 // 32^3 cells
#define IMG_H 1080
#define IMG_W 1920
#define TH 256
#define TW 256

// ---------------- Kernel A: W-resize (antialias triangle, kscale=7.5) -------
// img [B*3, 1080, 1920] -> tmp [B*3, 1080, 256]
__global__ void resize_w_kernel(const float* __restrict__ img,
                                float* __restrict__ tmp, int total) {
    int e = blockIdx.x * blockDim.x + threadIdx.x;
    if (e >= total) return;
    int ow = e & 255;
    int r  = e >> 8;            // row index over B*3*1080
    const float kscale = 7.5f;  // 1920/256
    float sf = (ow + 0.5f) * 7.5f - 0.5f;
    int lo = (int)ceilf(sf - kscale); if (lo < 0) lo = 0;
    int hi = (int)floorf(sf + kscale); if (hi > IMG_W - 1) hi = IMG_W - 1;
    const float* row = img + (size_t)r * IMG_W;
    float acc = 0.f, wsum = 0.f;
    for (int i = lo; i <= hi; ++i) {
        float w = 1.0f - fabsf(sf - (float)i) * (1.0f / 7.5f);
        if (w > 0.f) { acc += w * row[i]; wsum += w; }
    }
    tmp[e] = acc / wsum;
}

// ---------------- Kernel B: H-resize (kscale=4.21875) -----------------------
// tmp [B*3, 1080, 256] -> thumb [B*3, 256, 256]
__global__ void resize_h_kernel(const float* __restrict__ tmp,
                                float* __restrict__ thumb, int total) {
    int e = blockIdx.x * blockDim.x + threadIdx.x;
    if (e >= total) return;
    int ow = e & 255;
    int oh = (e >> 8) & 255;
    int pl = e >> 16;           // plane over B*3
    const float kscale = 4.21875f;  // 1080/256
    float sf = (oh + 0.5f) * 4.21875f - 0.5f;
    int lo = (int)ceilf(sf - kscale); if (lo < 0) lo = 0;
    int hi = (int)floorf(sf + kscale); if (hi > IMG_H - 1) hi = IMG_H - 1;
    const float* col = tmp + (size_t)pl * IMG_H * TW + ow;
    float acc = 0.f, wsum = 0.f;
    for (int i = lo; i <= hi; ++i) {
        float w = 1.0f - fabsf(sf - (float)i) * (1.0f / 4.21875f);
        if (w > 0.f) { acc += w * col[(size_t)i * TW]; wsum += w; }
    }
    thumb[e] = acc / wsum;
}

// ---------------- Kernel C1: conv1 3->16, stride2, SAME(pad_lo=0), relu ----
// thumb [B,3,256,256] -> c1 [B,16,128,128]
__global__ void conv1_kernel(const float* __restrict__ thumb,
                             const float* __restrict__ w,
                             const float* __restrict__ bias,
                             float* __restrict__ out, int total) {
    int e = blockIdx.x * blockDim.x + threadIdx.x;
    if (e >= total) return;
    int ow = e & 127;
    int oh = (e >> 7) & 127;
    int oc = (e >> 14) & 15;
    int b  = e >> 18;
    float acc = bias[oc];
    for (int ic = 0; ic < 3; ++ic) {
        const float* tp = thumb + ((size_t)(b * 3 + ic) * 256) * 256;
        const float* wp = w + ((oc * 3 + ic) * 9);
        #pragma unroll
        for (int kh = 0; kh < 3; ++kh) {
            int ih = oh * 2 + kh;
            if (ih >= 256) continue;
            #pragma unroll
            for (int kw = 0; kw < 3; ++kw) {
                int iw = ow * 2 + kw;
                if (iw >= 256) continue;
                acc += tp[ih * 256 + iw] * wp[kh * 3 + kw];
            }
        }
    }
    out[e] = fmaxf(acc, 0.f);
}

// ---------- Kernel C2+D1: conv2 16->32 s2 relu + per-wave partial pool ------
// c1 [B,16,128,128] -> partial [B*32, 64]  (wave w of group g sums its 64 px)
__global__ void conv2_pool_kernel(const float* __restrict__ c1,
                                  const float* __restrict__ w,
                                  const float* __restrict__ bias,
                                  float* __restrict__ partial, int total) {
    int e = blockIdx.x * blockDim.x + threadIdx.x;
    if (e >= total) return;
    int ow = e & 63;
    int oh = (e >> 6) & 63;
    int oc = (e >> 12) & 31;
    int b  = e >> 17;
    float acc = bias[oc];
    for (int ic = 0; ic < 16; ++ic) {
        const float* ip = c1 + ((size_t)(b * 16 + ic) * 128) * 128;
        const float* wp = w + ((oc * 16 + ic) * 9);
        #pragma unroll
        for (int kh = 0; kh < 3; ++kh) {
            int ih = oh * 2 + kh;
            if (ih >= 128) continue;
            #pragma unroll
            for (int kw = 0; kw < 3; ++kw) {
                int iw = ow * 2 + kw;
                if (iw >= 128) continue;
                acc += ip[ih * 128 + iw] * wp[kh * 3 + kw];
            }
        }
    }
    float val = fmaxf(acc, 0.f);
    // one wave = one oh row of one (b,oc): reduce 64 lanes -> partial
    #pragma unroll
    for (int off = 32; off > 0; off >>= 1) val += __shfl_down(val, off, 64);
    if (ow == 0) partial[((b * 32 + oc) << 6) + oh] = val;
}

// ------- Kernel D2: reduce partials + dense + softmax -> weights [B*3] ------
__global__ void head_kernel(const float* __restrict__ partial,
                            const float* __restrict__ dw,
                            const float* __restrict__ db,
                            float* __restrict__ wts, int B) {
    __shared__ float sp[8 * 32];
    __shared__ float lg[8 * 3];
    int t = threadIdx.x;
    if (t < B * 32) {
        const float* p = partial + (t << 6);
        float s = 0.f;
        #pragma unroll
        for (int i = 0; i < 64; ++i) s += p[i];
        sp[t] = s * (1.0f / 4096.0f);
    }
    __syncthreads();
    if (t < B * 3) {
        int b = t / 3, n = t - b * 3;
        float acc = db[n];
        for (int ch = 0; ch < 32; ++ch) acc += sp[b * 32 + ch] * dw[ch * 3 + n];
        lg[t] = acc;
    }
    __syncthreads();
    if (t < B) {
        float a = lg[t * 3 + 0], bb = lg[t * 3 + 1], c = lg[t * 3 + 2];
        float m = fmaxf(a, fmaxf(bb, c));
        float e0 = expf(a - m), e1 = expf(bb - m), e2 = expf(c - m);
        float inv = 1.0f / (e0 + e1 + e2);
        wts[t * 3 + 0] = e0 * inv;
        wts[t * 3 + 1] = e1 * inv;
        wts[t * 3 + 2] = e2 * inv;
    }
}

// ------- Kernel E: blend basis -> per-cell 64B records (8 fp16 corners) -----
// cells [B, 32768] x 4 float4. Record: half r[8], g[8], b[8], pad16.
// Corner index c = dz*4 + dy*2 + dx  (so half2 pair j = (z,y) with (x0,x1)).
__global__ void blend_cells_kernel(const float* __restrict__ basis,
                                   const float* __restrict__ wts,
                                   float4* __restrict__ cells, int total) {
    int e = blockIdx.x * blockDim.x + threadIdx.x;
    if (e >= total) return;
    int b    = e >> 15;
    int cidx = e & (CELLS - 1);
    int cx = cidx & 31, cy = (cidx >> 5) & 31, cz = cidx >> 10;
    float w0 = wts[b * 3 + 0], w1 = wts[b * 3 + 1], w2 = wts[b * 3 + 2];
    const float* b0 = basis;
    const float* b1 = basis + (size_t)LUT_P * 3;
    const float* b2 = basis + (size_t)2 * LUT_P * 3;
    union { float4 f4; __half h[8]; } ur, ug, ub;
    #pragma unroll
    for (int c = 0; c < 8; ++c) {
        int dx = c & 1, dy = (c >> 1) & 1, dz = c >> 2;
        size_t o = (size_t)(((cz + dz) * LUT_S + cy + dy) * LUT_S + cx + dx) * 3;
        ur.h[c] = __float2half_rn(w0 * b0[o + 0] + w1 * b1[o + 0] + w2 * b2[o + 0]);
        ug.h[c] = __float2half_rn(w0 * b0[o + 1] + w1 * b1[o + 1] + w2 * b2[o + 1]);
        ub.h[c] = __float2half_rn(w0 * b0[o + 2] + w1 * b1[o + 2] + w2 * b2[o + 2]);
    }
    float4* outp = cells + ((size_t)e << 2);
    outp[0] = ur.f4;
    outp[1] = ug.f4;
    outp[2] = ub.f4;
}

// ---------------- Kernel F: apply LUT via cell records, 4 px / thread -------
// ONE 64B-aligned record per pixel -> one 128B line touch per pixel.
__global__ __launch_bounds__(256)
void apply_lut_kernel(const float* __restrict__ img,
                      const float4* __restrict__ cells,
                      float* __restrict__ out, int total_quads) {
    const int P  = IMG_H * IMG_W;       // 2,073,600
    const int QP = P / 4;               // 518,400
    int t = blockIdx.x * blockDim.x + threadIdx.x;
    if (t >= total_quads) return;
    int b = t / QP;
    int q = t - b * QP;
    const float4* cbase = cells + ((size_t)b * CELLS << 2);
    size_t base = (size_t)b * 3 * P + (size_t)q * 4;
    float4 R  = *(const float4*)(img + base);
    float4 G  = *(const float4*)(img + base + P);
    float4 Bl = *(const float4*)(img + base + 2 * (size_t)P);
    float4 Ro, Go, Bo;
    float* rp = (float*)&R; float* gp = (float*)&G; float* bp = (float*)&Bl;
    float* rop = (float*)&Ro; float* gop = (float*)&Go; float* bop = (float*)&Bo;
    #pragma unroll
    for (int k = 0; k < 4; ++k) {
        float pr = fminf(fmaxf(rp[k], 0.f), 1.f) * (float)(LUT_S - 1);
        float pg = fminf(fmaxf(gp[k], 0.f), 1.f) * (float)(LUT_S - 1);
        float pb = fminf(fmaxf(bp[k], 0.f), 1.f) * (float)(LUT_S - 1);
        int ix = (int)pr; if (ix > LUT_S - 2) ix = LUT_S - 2;
        int iy = (int)pg; if (iy > LUT_S - 2) iy = LUT_S - 2;
        int iz = (int)pb; if (iz > LUT_S - 2) iz = LUT_S - 2;
        float fx = pr - (float)ix, fy = pg - (float)iy, fz = pb - (float)iz;
        // axis map: x<-R (fastest), y<-G, z<-B
        int cidx = (iz << 10) | (iy << 5) | ix;
        const float4* cp = cbase + ((size_t)cidx << 2);
        float4 fr = cp[0];
        float4 fg = cp[1];
        float4 fb = cp[2];
        float wx0 = 1.f - fx, wx1 = fx;
        float wy0 = 1.f - fy, wy1 = fy;
        float wz0 = 1.f - fz, wz1 = fz;
        const __half2* hr = (const __half2*)&fr;
        const __half2* hg = (const __half2*)&fg;
        const __half2* hb = (const __half2*)&fb;
        #pragma unroll
        for (int c = 0; c < 3; ++c) {
            const __half2* h = (c == 0) ? hr : (c == 1) ? hg : hb;
            float2 v00 = __half22float2(h[0]);   // (x0,x1) @ (y0,z0)
            float2 v10 = __half22float2(h[1]);   // (y1,z0)
            float2 v01 = __half22float2(h[2]);   // (y0,z1)
            float2 v11 = __half22float2(h[3]);   // (y1,z1)
            float x00 = v00.x * wx0 + v00.y * wx1;
            float x10 = v10.x * wx0 + v10.y * wx1;
            float x01 = v01.x * wx0 + v01.y * wx1;
            float x11 = v11.x * wx0 + v11.y * wx1;
            float z0 = x00 * wy0 + x10 * wy1;
            float z1 = x01 * wy0 + x11 * wy1;
            float o = fminf(fmaxf(z0 * wz0 + z1 * wz1, 0.f), 1.f);
            if (c == 0) rop[k] = o; else if (c == 1) gop[k] = o; else bop[k] = o;
        }
    }
    *(float4*)(out + base)                 = Ro;
    *(float4*)(out + base + P)             = Go;
    *(float4*)(out + base + 2 * (size_t)P) = Bo;
}

extern "C" void kernel_launch(void* const* d_in, const int* in_sizes, int n_in,
                              void* d_out, int out_size, void* d_ws, size_t ws_size,
                              hipStream_t stream) {
    const float* img     = (const float*)d_in[0];
    const float* basis   = (const float*)d_in[1];
    const float* conv1_w = (const float*)d_in[2];
    const float* conv1_b = (const float*)d_in[3];
    const float* conv2_w = (const float*)d_in[4];
    const float* conv2_b = (const float*)d_in[5];
    const float* dense_w = (const float*)d_in[6];
    const float* dense_b = (const float*)d_in[7];
    float* out = (float*)d_out;

    const size_t P = (size_t)IMG_H * IMG_W;
    int B = (int)(in_sizes[0] / (3 * P));   // 4

    // workspace layout (floats)
    float* ws = (float*)d_ws;
    size_t off = 0;
    float* tmp1    = ws + off; off += (size_t)B * 3 * IMG_H * TW;  // W-resized
    float* thumb   = ws + off; off += (size_t)B * 3 * TH * TW;
    float* c1      = ws + off; off += (size_t)B * 16 * 128 * 128;
    float* partial = ws + off; off += (size_t)B * 32 * 64;
    float* wts     = ws + off; off += (size_t)B * 3;
    off = (off + 3) & ~(size_t)3;                                  // 16B align
    float4* cells  = (float4*)(ws + off); off += (size_t)B * CELLS * 16;

    const int TPB = 256;
    {   // A: W-resize
        int total = B * 3 * IMG_H * TW;
        resize_w_kernel<<<(total + TPB - 1) / TPB, TPB, 0, stream>>>(img, tmp1, total);
    }
    {   // B: H-resize
        int total = B * 3 * TH * TW;
        resize_h_kernel<<<(total + TPB - 1) / TPB, TPB, 0, stream>>>(tmp1, thumb, total);
    }
    {   // C1
        int total = B * 16 * 128 * 128;
        conv1_kernel<<<(total + TPB - 1) / TPB, TPB, 0, stream>>>(thumb, conv1_w, conv1_b, c1, total);
    }
    {   // C2 + pool partials (no memset, no atomics)
        int total = B * 32 * 64 * 64;
        conv2_pool_kernel<<<(total + TPB - 1) / TPB, TPB, 0, stream>>>(c1, conv2_w, conv2_b, partial, total);
    }
    {   // D2: reduce + dense + softmax
        head_kernel<<<1, TPB, 0, stream>>>(partial, dense_w, dense_b, wts, B);
    }
    {   // E: blend -> cell records
        int total = B * CELLS;
        blend_cells_kernel<<<(total + TPB - 1) / TPB, TPB, 0, stream>>>(basis, wts, cells, total);
    }
    {   // F: apply
        int total = B * (int)(P / 4);
        apply_lut_kernel<<<(total + TPB - 1) / TPB, TPB, 0, stream>>>(img, cells, out, total);
    }
}

// Round 4
// 295.219 us; speedup vs baseline: 1.4777x; 1.2291x over previous
//
#include <hip/hip_runtime.h>
#include <hip/hip_bf16.h>
#include <hip/hip_fp16.h>

#define LUT_S 33
#define LUT_P (LUT_S*LUT_S*LUT_S)   // 35937
#define CELLS 32768                 // 32^3 cells
#define IMG_H 1080
#define IMG_W 1920
#define TH 256
#define TW 256

// ---------------- Kernel A: W-resize via LDS row staging --------------------
// img [B*3, 1080, 1920] -> tmp [B*3, 1080, 256]; one block per row.
__global__ __launch_bounds__(256)
void resize_w_kernel(const float* __restrict__ img, float* __restrict__ tmp) {
    __shared__ float srow[IMG_W];
    int r = blockIdx.x;                       // over B*3*1080 rows
    const float4* row4 = (const float4*)(img + (size_t)r * IMG_W);
    float4* s4 = (float4*)srow;
    for (int i = threadIdx.x; i < IMG_W / 4; i += 256) s4[i] = row4[i];
    __syncthreads();
    int ow = threadIdx.x;
    const float kscale = 7.5f;                // 1920/256
    float sf = (ow + 0.5f) * 7.5f - 0.5f;
    int lo = (int)ceilf(sf - kscale); if (lo < 0) lo = 0;
    int hi = (int)floorf(sf + kscale); if (hi > IMG_W - 1) hi = IMG_W - 1;
    float acc = 0.f, wsum = 0.f;
    for (int i = lo; i <= hi; ++i) {
        float w = 1.0f - fabsf(sf - (float)i) * (1.0f / 7.5f);
        if (w > 0.f) { acc += w * srow[i]; wsum += w; }
    }
    tmp[(size_t)r * TW + ow] = acc / wsum;
}

// ---------------- Kernel B: H-resize (kscale=4.21875), coalesced ------------
// tmp [B*3, 1080, 256] -> thumb [B*3, 256, 256]
__global__ void resize_h_kernel(const float* __restrict__ tmp,
                                float* __restrict__ thumb, int total) {
    int e = blockIdx.x * blockDim.x + threadIdx.x;
    if (e >= total) return;
    int ow = e & 255;
    int oh = (e >> 8) & 255;
    int pl = e >> 16;           // plane over B*3
    const float kscale = 4.21875f;  // 1080/256
    float sf = (oh + 0.5f) * 4.21875f - 0.5f;
    int lo = (int)ceilf(sf - kscale); if (lo < 0) lo = 0;
    int hi = (int)floorf(sf + kscale); if (hi > IMG_H - 1) hi = IMG_H - 1;
    const float* col = tmp + (size_t)pl * IMG_H * TW + ow;
    float acc = 0.f, wsum = 0.f;
    for (int i = lo; i <= hi; ++i) {
        float w = 1.0f - fabsf(sf - (float)i) * (1.0f / 4.21875f);
        if (w > 0.f) { acc += w * col[(size_t)i * TW]; wsum += w; }
    }
    thumb[e] = acc / wsum;
}

// ------- Kernel C1: conv1 3->16 s2 SAME(pad_lo=0) relu, 16 oc / thread ------
// thumb [B,3,256,256] -> c1 [B,16,128,128]
__global__ void conv1_kernel(const float* __restrict__ thumb,
                             const float* __restrict__ w,
                             const float* __restrict__ bias,
                             float* __restrict__ out, int total) {
    int e = blockIdx.x * blockDim.x + threadIdx.x;
    if (e >= total) return;                   // total = B*128*128
    int ow = e & 127;
    int oh = (e >> 7) & 127;
    int b  = e >> 14;
    float acc[16];
    #pragma unroll
    for (int oc = 0; oc < 16; ++oc) acc[oc] = bias[oc];
    for (int ic = 0; ic < 3; ++ic) {
        const float* tp = thumb + ((size_t)(b * 3 + ic) * 256) * 256;
        #pragma unroll
        for (int kh = 0; kh < 3; ++kh) {
            int ih = oh * 2 + kh;
            if (ih >= 256) continue;
            #pragma unroll
            for (int kw = 0; kw < 3; ++kw) {
                int iw = ow * 2 + kw;
                if (iw >= 256) continue;
                float v = tp[ih * 256 + iw];
                #pragma unroll
                for (int oc = 0; oc < 16; ++oc)
                    acc[oc] += v * w[(oc * 3 + ic) * 9 + kh * 3 + kw];
            }
        }
    }
    size_t o = ((size_t)b * 16 << 14) + (oh << 7) + ow;
    #pragma unroll
    for (int oc = 0; oc < 16; ++oc)
        out[o + ((size_t)oc << 14)] = fmaxf(acc[oc], 0.f);
}

// -- Kernel C2+D1: conv2 16->32 s2 relu + pool, 8 oc / thread, wave-reduce ---
// c1 [B,16,128,128] -> partial [B*32, 64]
__global__ void conv2_pool_kernel(const float* __restrict__ c1,
                                  const float* __restrict__ w,
                                  const float* __restrict__ bias,
                                  float* __restrict__ partial, int total) {
    int e = blockIdx.x * blockDim.x + threadIdx.x;
    if (e >= total) return;                   // total = B*4*4096
    int sp = e & 4095;                        // oh*64+ow
    int g  = (e >> 12) & 3;                   // oc group (8 each)
    int b  = e >> 14;
    int ow = sp & 63, oh = sp >> 6;
    float acc[8];
    #pragma unroll
    for (int j = 0; j < 8; ++j) acc[j] = bias[g * 8 + j];
    for (int ic = 0; ic < 16; ++ic) {
        const float* ip = c1 + ((size_t)(b * 16 + ic) << 14);
        #pragma unroll
        for (int kh = 0; kh < 3; ++kh) {
            int ih = oh * 2 + kh;
            if (ih >= 128) continue;
            #pragma unroll
            for (int kw = 0; kw < 3; ++kw) {
                int iw = ow * 2 + kw;
                if (iw >= 128) continue;
                float v = ip[(ih << 7) + iw];
                #pragma unroll
                for (int j = 0; j < 8; ++j)
                    acc[j] += v * w[((g * 8 + j) * 16 + ic) * 9 + kh * 3 + kw];
            }
        }
    }
    #pragma unroll
    for (int j = 0; j < 8; ++j) {
        float val = fmaxf(acc[j], 0.f);
        #pragma unroll
        for (int off = 32; off > 0; off >>= 1) val += __shfl_down(val, off, 64);
        acc[j] = val;
    }
    // wave = 64 consecutive e -> full ow row, fixed (b,g,oh)
    if ((threadIdx.x & 63) == 0) {
        #pragma unroll
        for (int j = 0; j < 8; ++j)
            partial[((b * 32 + g * 8 + j) << 6) + oh] = acc[j];
    }
}

// ------- Kernel D2: reduce partials + dense + softmax -> weights [B*3] ------
__global__ void head_kernel(const float* __restrict__ partial,
                            const float* __restrict__ dw,
                            const float* __restrict__ db,
                            float* __restrict__ wts, int B) {
    __shared__ float sp[8 * 32];
    __shared__ float lg[8 * 3];
    int t = threadIdx.x;
    if (t < B * 32) {
        const float4* p4 = (const float4*)(partial + (t << 6));
        float s = 0.f;
        #pragma unroll
        for (int i = 0; i < 16; ++i) {
            float4 v = p4[i];
            s += v.x + v.y + v.z + v.w;
        }
        sp[t] = s * (1.0f / 4096.0f);
    }
    __syncthreads();
    if (t < B * 3) {
        int b = t / 3, n = t - b * 3;
        float acc = db[n];
        for (int ch = 0; ch < 32; ++ch) acc += sp[b * 32 + ch] * dw[ch * 3 + n];
        lg[t] = acc;
    }
    __syncthreads();
    if (t < B) {
        float a = lg[t * 3 + 0], bb = lg[t * 3 + 1], c = lg[t * 3 + 2];
        float m = fmaxf(a, fmaxf(bb, c));
        float e0 = expf(a - m), e1 = expf(bb - m), e2 = expf(c - m);
        float inv = 1.0f / (e0 + e1 + e2);
        wts[t * 3 + 0] = e0 * inv;
        wts[t * 3 + 1] = e1 * inv;
        wts[t * 3 + 2] = e2 * inv;
    }
}

// --- Kernel E: blend basis -> 32B u8 cell records ---------------------------
// Record (32 B, uint4 x2): bytes 0-7 r corners c0..7 (c=dz*4+dy*2+dx),
// 8-15 g, 16-23 b, dword6 = scale(f32), dword7 = offset(f32).
// value = q * scale + offset.
__global__ void blend_cells_kernel(const float* __restrict__ basis,
                                   const float* __restrict__ wts,
                                   uint4* __restrict__ cells, int total) {
    int e = blockIdx.x * blockDim.x + threadIdx.x;
    if (e >= total) return;
    int b    = e >> 15;
    int cidx = e & (CELLS - 1);
    int cx = cidx & 31, cy = (cidx >> 5) & 31, cz = cidx >> 10;
    float w0 = wts[b * 3 + 0], w1 = wts[b * 3 + 1], w2 = wts[b * 3 + 2];
    const float* b0 = basis;
    const float* b1 = basis + (size_t)LUT_P * 3;
    const float* b2 = basis + (size_t)2 * LUT_P * 3;
    float v[24];   // [ch*8 + c]
    float mn = 1e30f, mx = -1e30f;
    #pragma unroll
    for (int c = 0; c < 8; ++c) {
        int dx = c & 1, dy = (c >> 1) & 1, dz = c >> 2;
        size_t o = (size_t)(((cz + dz) * LUT_S + cy + dy) * LUT_S + cx + dx) * 3;
        #pragma unroll
        for (int ch = 0; ch < 3; ++ch) {
            float val = w0 * b0[o + ch] + w1 * b1[o + ch] + w2 * b2[o + ch];
            v[ch * 8 + c] = val;
            mn = fminf(mn, val); mx = fmaxf(mx, val);
        }
    }
    float range = mx - mn;
    float inv = (range > 1e-20f) ? 255.0f / range : 0.0f;
    float scale = range * (1.0f / 255.0f);
    unsigned int d[6];
    #pragma unroll
    for (int k = 0; k < 6; ++k) {
        unsigned int pk = 0;
        #pragma unroll
        for (int j = 0; j < 4; ++j) {
            float q = (v[k * 4 + j] - mn) * inv;
            int qi = (int)rintf(q);
            qi = qi < 0 ? 0 : (qi > 255 ? 255 : qi);
            pk |= ((unsigned int)qi) << (8 * j);
        }
        d[k] = pk;
    }
    uint4* outp = cells + ((size_t)e << 1);
    outp[0] = make_uint4(d[0], d[1], d[2], d[3]);
    outp[1] = make_uint4(d[4], d[5], __float_as_uint(scale), __float_as_uint(mn));
}

// ---------------- Kernel F: apply LUT via u8 cell records, 4 px / thread ----
// TWO 16B gathers per pixel (one 128B line).
__device__ __forceinline__ float trilerp_u8(unsigned int lo, unsigned int hi,
                                            float fx, float fy, float fz) {
    float q000 = (float)(lo & 0xffu);
    float q100 = (float)((lo >> 8) & 0xffu);
    float q010 = (float)((lo >> 16) & 0xffu);
    float q110 = (float)((lo >> 24) & 0xffu);
    float q001 = (float)(hi & 0xffu);
    float q101 = (float)((hi >> 8) & 0xffu);
    float q011 = (float)((hi >> 16) & 0xffu);
    float q111 = (float)((hi >> 24) & 0xffu);
    float a0 = q000 + fx * (q100 - q000);
    float a1 = q010 + fx * (q110 - q010);
    float b0 = q001 + fx * (q101 - q001);
    float b1 = q011 + fx * (q111 - q011);
    float c0 = a0 + fy * (a1 - a0);
    float c1 = b0 + fy * (b1 - b0);
    return c0 + fz * (c1 - c0);
}

__global__ __launch_bounds__(256)
void apply_lut_kernel(const float* __restrict__ img,
                      const uint4* __restrict__ cells,
                      float* __restrict__ out, int total_quads) {
    const int P  = IMG_H * IMG_W;       // 2,073,600
    const int QP = P / 4;               // 518,400
    int t = blockIdx.x * blockDim.x + threadIdx.x;
    if (t >= total_quads) return;
    int b = t / QP;
    int q = t - b * QP;
    const uint4* cbase = cells + ((size_t)b * CELLS << 1);
    size_t base = (size_t)b * 3 * P + (size_t)q * 4;
    float4 R  = *(const float4*)(img + base);
    float4 G  = *(const float4*)(img + base + P);
    float4 Bl = *(const float4*)(img + base + 2 * (size_t)P);
    float4 Ro, Go, Bo;
    float* rp = (float*)&R; float* gp = (float*)&G; float* bp = (float*)&Bl;
    float* rop = (float*)&Ro; float* gop = (float*)&Go; float* bop = (float*)&Bo;
    #pragma unroll
    for (int k = 0; k < 4; ++k) {
        float pr = fminf(fmaxf(rp[k], 0.f), 1.f) * (float)(LUT_S - 1);
        float pg = fminf(fmaxf(gp[k], 0.f), 1.f) * (float)(LUT_S - 1);
        float pb = fminf(fmaxf(bp[k], 0.f), 1.f) * (float)(LUT_S - 1);
        int ix = (int)pr; if (ix > LUT_S - 2) ix = LUT_S - 2;
        int iy = (int)pg; if (iy > LUT_S - 2) iy = LUT_S - 2;
        int iz = (int)pb; if (iz > LUT_S - 2) iz = LUT_S - 2;
        float fx = pr - (float)ix, fy = pg - (float)iy, fz = pb - (float)iz;
        // axis map: x<-R (fastest), y<-G, z<-B
        int cidx = (iz << 10) | (iy << 5) | ix;
        const uint4* cp = cbase + ((size_t)cidx << 1);
        uint4 A  = cp[0];   // r lo/hi, g lo/hi
        uint4 Bq = cp[1];   // b lo/hi, scale, offset
        float scale = __uint_as_float(Bq.z);
        float offs  = __uint_as_float(Bq.w);
        float tr = trilerp_u8(A.x, A.y, fx, fy, fz);
        float tg = trilerp_u8(A.z, A.w, fx, fy, fz);
        float tb = trilerp_u8(Bq.x, Bq.y, fx, fy, fz);
        rop[k] = fminf(fmaxf(tr * scale + offs, 0.f), 1.f);
        gop[k] = fminf(fmaxf(tg * scale + offs, 0.f), 1.f);
        bop[k] = fminf(fmaxf(tb * scale + offs, 0.f), 1.f);
    }
    *(float4*)(out + base)                 = Ro;
    *(float4*)(out + base + P)             = Go;
    *(float4*)(out + base + 2 * (size_t)P) = Bo;
}

extern "C" void kernel_launch(void* const* d_in, const int* in_sizes, int n_in,
                              void* d_out, int out_size, void* d_ws, size_t ws_size,
                              hipStream_t stream) {
    const float* img     = (const float*)d_in[0];
    const float* basis   = (const float*)d_in[1];
    const float* conv1_w = (const float*)d_in[2];
    const float* conv1_b = (const float*)d_in[3];
    const float* conv2_w = (const float*)d_in[4];
    const float* conv2_b = (const float*)d_in[5];
    const float* dense_w = (const float*)d_in[6];
    const float* dense_b = (const float*)d_in[7];
    float* out = (float*)d_out;

    const size_t P = (size_t)IMG_H * IMG_W;
    int B = (int)(in_sizes[0] / (3 * P));   // 4

    // workspace layout (floats)
    float* ws = (float*)d_ws;
    size_t off = 0;
    float* tmp1    = ws + off; off += (size_t)B * 3 * IMG_H * TW;  // W-resized
    float* thumb   = ws + off; off += (size_t)B * 3 * TH * TW;
    float* c1      = ws + off; off += (size_t)B * 16 * 128 * 128;
    float* partial = ws + off; off += (size_t)B * 32 * 64;
    float* wts     = ws + off; off += (size_t)B * 3;
    off = (off + 3) & ~(size_t)3;                                  // 16B align
    uint4* cells   = (uint4*)(ws + off); off += (size_t)B * CELLS * 8;

    const int TPB = 256;
    {   // A: W-resize (one block per row)
        resize_w_kernel<<<B * 3 * IMG_H, TPB, 0, stream>>>(img, tmp1);
    }
    {   // B: H-resize
        int total = B * 3 * TH * TW;
        resize_h_kernel<<<(total + TPB - 1) / TPB, TPB, 0, stream>>>(tmp1, thumb, total);
    }
    {   // C1: 16 oc / thread
        int total = B * 128 * 128;
        conv1_kernel<<<(total + TPB - 1) / TPB, TPB, 0, stream>>>(thumb, conv1_w, conv1_b, c1, total);
    }
    {   // C2 + pool: 8 oc / thread, 4 groups
        int total = B * 4 * 4096;
        conv2_pool_kernel<<<(total + TPB - 1) / TPB, TPB, 0, stream>>>(c1, conv2_w, conv2_b, partial, total);
    }
    {   // D2: reduce + dense + softmax
        head_kernel<<<1, TPB, 0, stream>>>(partial, dense_w, dense_b, wts, B);
    }
    {   // E: blend -> u8 cell records
        int total = B * CELLS;
        blend_cells_kernel<<<(total + TPB - 1) / TPB, TPB, 0, stream>>>(basis, wts, cells, total);
    }
    {   // F: apply
        int total = B * (int)(P / 4);
        apply_lut_kernel<<<(total + TPB - 1) / TPB, TPB, 0, stream>>>(img, cells, out, total);
    }
}